// Round 7
// baseline (124.045 us; speedup 1.0000x reference)
//
#include <hip/hip_runtime.h>
#include <hip/hip_bf16.h>
#include <stdint.h>

// Problem constants: B=2, T=1024, D=1024, N=16
#define TT 1024
#define BB 2
#define DD 1024
#define NN 16
#define NCH 64   // chunks
#define LCH 16   // chunk length (NCH*LCH == TT)

#define K_STEEP 10.0f
#define V_TH_MIN 0.1f
#define L2E 1.44269504088896f

typedef __bf16 bf16x8 __attribute__((ext_vector_type(8)));
typedef float f32x4 __attribute__((ext_vector_type(4)));

__device__ __forceinline__ short f2bf(float f) {
    union { float f; unsigned u; } c; c.f = f;
    unsigned r = (c.u + 0x7fffu + ((c.u >> 16) & 1u)) >> 16;
    return (short)r;
}
__device__ __forceinline__ float bf2f(short s) {
    union { unsigned u; float f; } c;
    c.u = ((unsigned)(unsigned short)s) << 16;
    return c.f;
}

__device__ __forceinline__ void gload_lds16(const void* g, void* l) {
    __builtin_amdgcn_global_load_lds(
        (const __attribute__((address_space(1))) void*)g,
        (__attribute__((address_space(3))) void*)l, 16, 0, 0);
}

// ---------------------------------------------------------------------------
// bf16 MFMA GEMM: C[M][N] = A[M][K] @ BT[N][K]^T  (+ epilogue)
// Tile BM x 128, BK=32, 256 threads (4 waves, 2x2).  A has row stride lda.
// EPI 0: plain fp32 store
// EPI 1: softplus(v + bias[col])
// EPI 2: v - sub[row*ldc + col]
// EPI 3: bf16-only store into bf16out[row*ldc + col]
// FUSE_BC: blocks with blockIdx.x == gridDim.x-1 instead compute
//   bcout[32 rows][32] = A[by*32 .. +32][K] @ WbcT[32][K]^T   (BK=64)
// ---------------------------------------------------------------------------
template<int BM, int EPI, bool FUSE_BC>
__global__ __launch_bounds__(256) void gemm_mfma(
    const short* __restrict__ A, int lda,
    const short* __restrict__ BT,
    float* __restrict__ C, int ldc,
    int M, int Ncols, int K,
    const float* __restrict__ bias,
    const float* __restrict__ sub,
    short* __restrict__ bf16out,
    const short* __restrict__ WbcT,
    float* __restrict__ bcout)
{
    constexpr int RI = BM / 32;          // row frags per wave
    constexpr int AS_SZ = (FUSE_BC && BM * 32 < 2048) ? 2048 : BM * 32;
    __shared__ short As[AS_SZ];          // GEMM: [row][32k]; bc: [32row][64k]
    __shared__ short Bs[128 * 32];       // GEMM: [n][32k]; bc: [32n][64k]

    const int tid = threadIdx.x;
    const int wave = tid >> 6, lane = tid & 63;
    const int kk = (lane >> 4) * 8;
    const int r16 = lane & 15;
    const int wr = wave >> 1, wc = wave & 1;

    if (FUSE_BC && blockIdx.x == gridDim.x - 1) {
        // ---- bc path: 32 rows x 32 cols, BK=64 ----
        const int bm2 = blockIdx.y * 32;
        f32x4 acc2 = {};
        for (int k0 = 0; k0 < K; k0 += 64) {
            int off = tid * 16;
            int row = off >> 7;            // 128B per row (64 bf16)
            int ke  = (off & 127) >> 1;
            gload_lds16(A + (size_t)(bm2 + row) * lda + k0 + ke, (char*)As + off);
            gload_lds16(WbcT + (size_t)row * K + k0 + ke, (char*)Bs + off);
            __syncthreads();
            bf16x8 alo = *(const bf16x8*)&As[(wr * 16 + r16) * 64 + kk];
            bf16x8 ahi = *(const bf16x8*)&As[(wr * 16 + r16) * 64 + kk + 32];
            bf16x8 blo = *(const bf16x8*)&Bs[(wc * 16 + r16) * 64 + kk];
            bf16x8 bhi = *(const bf16x8*)&Bs[(wc * 16 + r16) * 64 + kk + 32];
            acc2 = __builtin_amdgcn_mfma_f32_16x16x32_bf16(alo, blo, acc2, 0, 0, 0);
            acc2 = __builtin_amdgcn_mfma_f32_16x16x32_bf16(ahi, bhi, acc2, 0, 0, 0);
            __syncthreads();
        }
        #pragma unroll
        for (int g = 0; g < 4; g++) {
            int row = bm2 + wr * 16 + (lane >> 4) * 4 + g;
            int col = wc * 16 + r16;
            bcout[(size_t)row * 32 + col] = acc2[g];
        }
        return;
    }

    const int bm = blockIdx.y * BM, bn = blockIdx.x * 128;
    f32x4 acc[RI][4] = {};

    for (int k0 = 0; k0 < K; k0 += 32) {
        // stage B tile: 8192B, 2 x 16B per thread
        #pragma unroll
        for (int it = 0; it < 2; it++) {
            int off = it * 4096 + tid * 16;
            int row = off >> 6;             // 64B per row (32 bf16)
            int ke  = (off & 63) >> 1;
            gload_lds16(BT + (size_t)(bn + row) * K + k0 + ke, (char*)Bs + off);
        }
        // stage A tile: BM*64 bytes
        if (tid < BM * 4) {
            int off = tid * 16;
            int row = off >> 6;
            int ke  = (off & 63) >> 1;
            gload_lds16(A + (size_t)(bm + row) * lda + k0 + ke, (char*)As + off);
        }
        __syncthreads();

        bf16x8 a[RI], b[4];
        #pragma unroll
        for (int i = 0; i < RI; i++)
            a[i] = *(const bf16x8*)&As[(wr * (BM / 2) + i * 16 + r16) * 32 + kk];
        #pragma unroll
        for (int j = 0; j < 4; j++)
            b[j] = *(const bf16x8*)&Bs[(wc * 64 + j * 16 + r16) * 32 + kk];
        #pragma unroll
        for (int i = 0; i < RI; i++)
            #pragma unroll
            for (int j = 0; j < 4; j++)
                acc[i][j] = __builtin_amdgcn_mfma_f32_16x16x32_bf16(
                    a[i], b[j], acc[i][j], 0, 0, 0);
        __syncthreads();
    }

    // epilogue: C/D layout col = lane&15, row = (lane>>4)*4 + reg (m89/m91)
    #pragma unroll
    for (int i = 0; i < RI; i++) {
        #pragma unroll
        for (int j = 0; j < 4; j++) {
            #pragma unroll
            for (int g = 0; g < 4; g++) {
                int row = bm + wr * (BM / 2) + i * 16 + (lane >> 4) * 4 + g;
                int col = bn + wc * 64 + j * 16 + r16;
                float v = acc[i][j][g];
                if (EPI == 3) {
                    bf16out[(size_t)row * ldc + col] = f2bf(v);
                } else {
                    if (EPI == 1) {
                        v += bias[col];
                        v = fmaxf(v, 0.f) + log1pf(__expf(-fabsf(v)));
                    }
                    if (EPI == 2) {
                        v -= sub[(size_t)row * ldc + col];
                    }
                    C[(size_t)row * ldc + col] = v;
                }
            }
        }
    }
}

// ---------------------------------------------------------------------------
// 32x32 fp32->bf16 transpose tile (shared helper for prep kernel)
// ---------------------------------------------------------------------------
__device__ __forceinline__ void tr_tile(
    const float* __restrict__ W, short* __restrict__ WT,
    int K, int N, int k0, int n0, int tid)
{
    __shared__ float t[32][33];
    int r = tid >> 3, q = tid & 7;
    float4 v = *(const float4*)&W[(size_t)(k0 + r) * N + n0 + q * 4];
    t[r][q * 4 + 0] = v.x; t[r][q * 4 + 1] = v.y;
    t[r][q * 4 + 2] = v.z; t[r][q * 4 + 3] = v.w;
    __syncthreads();
    short4 o = { f2bf(t[q * 4 + 0][r]), f2bf(t[q * 4 + 1][r]),
                 f2bf(t[q * 4 + 2][r]), f2bf(t[q * 4 + 3][r]) };
    *(short4*)&WT[(size_t)(n0 + r) * K + k0 + q * 4] = o;
}

// ---------------------------------------------------------------------------
// One-shot prep: all fp32->bf16 converts/transposes in a single launch.
// blocks [0,2048): H->Hb        [2048,4096): W_xz^T   [4096,5120): W_dt^T
// [5120,6144): W_out^T          [6144,6272): W_B|W_C pack
// ---------------------------------------------------------------------------
__global__ __launch_bounds__(256) void prep_all(
    const float* __restrict__ H,    short* __restrict__ Hb,
    const float* __restrict__ W_xz, short* __restrict__ WxzT,
    const float* __restrict__ W_dt, short* __restrict__ WdtT,
    const float* __restrict__ W_out,short* __restrict__ WoutT,
    const float* __restrict__ W_B,  const float* __restrict__ W_C,
    short* __restrict__ WbcT)
{
    int bid = blockIdx.x, tid = threadIdx.x;
    if (bid < 2048) {
        int i = bid * 1024 + tid * 4;
        float4 v = *(const float4*)&H[i];
        short4 o = { f2bf(v.x), f2bf(v.y), f2bf(v.z), f2bf(v.w) };
        *(short4*)&Hb[i] = o;
    } else if (bid < 4096) {
        int t = bid - 2048;                       // 64 n-tiles x 32 k-tiles
        tr_tile(W_xz, WxzT, DD, 2 * DD, (t >> 6) * 32, (t & 63) * 32, tid);
    } else if (bid < 5120) {
        int t = bid - 4096;
        tr_tile(W_dt, WdtT, DD, DD, (t >> 5) * 32, (t & 31) * 32, tid);
    } else if (bid < 6144) {
        int t = bid - 5120;
        tr_tile(W_out, WoutT, DD, DD, (t >> 5) * 32, (t & 31) * 32, tid);
    } else {
        int g = (bid - 6144) * 256 + tid;         // 0..32767
        int k = g & (DD - 1);
        int n = g >> 10;
        float v = (n < 16) ? W_B[(size_t)k * NN + n]
                           : W_C[(size_t)k * NN + n - 16];
        WbcT[(size_t)n * DD + k] = f2bf(v);
    }
}

// ---------------------------------------------------------------------------
// Phase 1: per (b,d,chunk) local scan with s0=0.  d = blockIdx.x*256+tid
// (fully coalesced: 64 lanes read 64 consecutive d).
// ---------------------------------------------------------------------------
__global__ __launch_bounds__(256) void scan_phase1(
    const short* __restrict__ xzb,    // [2048][2048] bf16 (x | z)
    const float* __restrict__ dtb,    // [2048][1024] fp32
    const float* __restrict__ bc,     // [2048][32] fp32
    const float* __restrict__ A_log,
    float* __restrict__ Lst,          // [NCH][BB][DD][NN]
    float* __restrict__ sdt)          // [NCH][BB][DD]
{
    int tid = threadIdx.x;
    int d = blockIdx.x * 256 + tid;
    int b = blockIdx.y;
    int c = blockIdx.z;

    __shared__ float sBm[LCH][NN];
    {
        int j = tid >> 4, n = tid & 15;
        int r = b * TT + c * LCH + j;
        sBm[j][n] = bc[(size_t)r * 32 + n];
    }
    __syncthreads();

    float a2[NN];
    #pragma unroll
    for (int n = 0; n < NN; n++)
        a2[n] = -__expf(A_log[(size_t)d * NN + n]) * L2E;

    float s[NN];
    #pragma unroll
    for (int n = 0; n < NN; n++) s[n] = 0.f;

    float sum_dt = 0.f;
    for (int j = 0; j < LCH; j++) {
        int r = b * TT + c * LCH + j;
        float dt = dtb[(size_t)r * DD + d];
        float x  = bf2f(xzb[(size_t)r * (2 * DD) + d]);
        float dtx = dt * x;
        sum_dt += dt;
        #pragma unroll
        for (int n = 0; n < NN; n++) {
            float dec = exp2f(a2[n] * dt);
            s[n] = fmaf(dec, s[n], dtx * sBm[j][n]);
        }
    }
    size_t base = ((size_t)(c * BB + b) * DD + d) * NN;
    #pragma unroll
    for (int n = 0; n < NN; n++) Lst[base + n] = s[n];
    sdt[(size_t)(c * BB + b) * DD + d] = sum_dt;
}

// ---------------------------------------------------------------------------
// Phase 2: combine chunk boundaries.  thread per (b,d,n), n fastest.
// ---------------------------------------------------------------------------
__global__ __launch_bounds__(256) void scan_phase2(
    const float* __restrict__ A_log,
    const float* __restrict__ Lst,
    const float* __restrict__ sdt,
    float* __restrict__ Sinit)
{
    int g = blockIdx.x * 256 + threadIdx.x;
    int n = g & 15;
    int d = (g >> 4) & (DD - 1);
    int b = g >> 14;
    float a2 = -__expf(A_log[(size_t)d * NN + n]) * L2E;
    float s = 0.f;
    for (int c = 0; c < NCH; c++) {
        size_t idx = ((size_t)(c * BB + b) * DD + d) * NN + n;
        Sinit[idx] = s;
        float P = exp2f(a2 * sdt[(size_t)(c * BB + b) * DD + d]);
        s = fmaf(P, s, Lst[idx]);
    }
}

// ---------------------------------------------------------------------------
// Phase 3: replay with correct init; g = y*spike*silu(z) stored bf16.
// ---------------------------------------------------------------------------
__global__ __launch_bounds__(256) void scan_phase3(
    const short* __restrict__ xzb,
    const float* __restrict__ dtb,
    const float* __restrict__ bc,
    const float* __restrict__ A_log,
    const float* __restrict__ Sinit,
    const float* __restrict__ D_skip,
    const float* __restrict__ v_th,
    short* __restrict__ gout)
{
    int tid = threadIdx.x;
    int d = blockIdx.x * 256 + tid;
    int b = blockIdx.y;
    int c = blockIdx.z;

    __shared__ float sB[LCH][NN];
    __shared__ float sC[LCH][NN];
    {
        int j = tid >> 5, m = tid & 31;        // covers 8 rows per pass
        #pragma unroll
        for (int p = 0; p < 2; p++) {
            int jj = j + p * 8;
            int r = b * TT + c * LCH + jj;
            float v = bc[(size_t)r * 32 + m];
            if (m < 16) sB[jj][m] = v; else sC[jj][m - 16] = v;
        }
    }
    __syncthreads();

    float a2[NN];
    #pragma unroll
    for (int n = 0; n < NN; n++)
        a2[n] = -__expf(A_log[(size_t)d * NN + n]) * L2E;

    size_t base = ((size_t)(c * BB + b) * DD + d) * NN;
    float s[NN];
    #pragma unroll
    for (int n = 0; n < NN; n++) s[n] = Sinit[base + n];

    float dsk = D_skip[d];
    float vth = fmaxf(v_th[d], V_TH_MIN);

    for (int j = 0; j < LCH; j++) {
        int r = b * TT + c * LCH + j;
        float dt = dtb[(size_t)r * DD + d];
        float x  = bf2f(xzb[(size_t)r * (2 * DD) + d]);
        float z  = bf2f(xzb[(size_t)r * (2 * DD) + DD + d]);
        float dtx = dt * x;
        float y = 0.f;
        #pragma unroll
        for (int n = 0; n < NN; n++) {
            float dec = exp2f(a2[n] * dt);
            s[n] = fmaf(dec, s[n], dtx * sB[j][n]);
            y = fmaf(s[n], sC[j][n], y);
        }
        y = fmaf(dsk, x, y);
        float sp = 1.f / (1.f + __expf(-K_STEEP * (y - vth)));
        float sz = z / (1.f + __expf(-z));
        gout[(size_t)r * DD + d] = f2bf(y * sp * sz);
    }
}

// ---------------------------------------------------------------------------
extern "C" void kernel_launch(void* const* d_in, const int* in_sizes, int n_in,
                              void* d_out, int out_size, void* d_ws, size_t ws_size,
                              hipStream_t stream) {
    const float* H      = (const float*)d_in[0];   // (2,1024,1024)
    const float* W_xz   = (const float*)d_in[1];   // (1024,2048)
    const float* W_dt   = (const float*)d_in[2];   // (1024,1024)
    const float* b_dt   = (const float*)d_in[3];   // (1024,)
    const float* A_log  = (const float*)d_in[4];   // (1024,16)
    const float* W_B    = (const float*)d_in[5];   // (1024,16)
    const float* W_C    = (const float*)d_in[6];   // (1024,16)
    const float* D_skip = (const float*)d_in[7];   // (1024,)
    const float* W_out  = (const float*)d_in[8];   // (1024,1024)
    const float* v_th   = (const float*)d_in[9];   // (1024,)
    float* out = (float*)d_out;

    // flat ws layout (~70 MB of 268 MB) — no aliasing
    float* ws  = (float*)d_ws;
    float* dtb = ws;                   // 2097152 f
    float* bcb = dtb + 2097152;        // 65536 f
    float* Lst = bcb + 65536;          // NCH*BB*DD*NN = 2097152 f
    float* sdt = Lst + 2097152;        // NCH*BB*DD    = 131072 f
    float* Sin = sdt + 131072;         // 2097152 f
    short* p16   = (short*)(Sin + 2097152);
    short* xzb   = p16;                // 4194304 s  (bf16 x|z)
    short* Hb    = xzb   + 4194304;    // 2097152 s
    short* WxzT  = Hb    + 2097152;    // 2097152 s
    short* WdtT  = WxzT  + 2097152;    // 1048576 s
    short* WoutT = WdtT  + 1048576;    // 1048576 s
    short* WbcT  = WoutT + 1048576;    // 32768 s
    short* gb    = WbcT  + 32768;      // 2097152 s

    const int M = BB * TT;  // 2048

    // 0) all converts in one launch
    prep_all<<<6272, 256, 0, stream>>>(
        H, Hb, W_xz, WxzT, W_dt, WdtT, W_out, WoutT, W_B, W_C, WbcT);
    // 1) xz = H @ W_xz (bf16 store) with bc fused as extra grid column
    gemm_mfma<32, 3, true><<<dim3(17, M / 32), 256, 0, stream>>>(
        Hb, DD, WxzT, nullptr, 2 * DD, M, 2 * DD, DD,
        nullptr, nullptr, xzb, WbcT, bcb);
    // 2) dt = softplus(x @ W_dt + b_dt)  (A = x-half of xzb, lda = 2048)
    gemm_mfma<32, 1, false><<<dim3(8, M / 32), 256, 0, stream>>>(
        xzb, 2 * DD, WdtT, dtb, DD, M, DD, DD,
        b_dt, nullptr, nullptr, nullptr, nullptr);
    // 3) chunked scan, coalesced d-mapping
    scan_phase1<<<dim3(DD / 256, BB, NCH), 256, 0, stream>>>(
        xzb, dtb, bcb, A_log, Lst, sdt);
    scan_phase2<<<(BB * DD * NN) / 256, 256, 0, stream>>>(A_log, Lst, sdt, Sin);
    scan_phase3<<<dim3(DD / 256, BB, NCH), 256, 0, stream>>>(
        xzb, dtb, bcb, A_log, Sin, D_skip, v_th, gb);
    // 4) out = g @ W_out - H
    gemm_mfma<32, 2, false><<<dim3(8, M / 32), 256, 0, stream>>>(
        gb, DD, WoutT, out, DD, M, DD, DD,
        nullptr, H, nullptr, nullptr, nullptr);
}